// Round 4
// baseline (162.124 us; speedup 1.0000x reference)
//
#include <hip/hip_runtime.h>

// ClusterPrior: B=8, N=4096, D=128, K=1024
// Round 4: MFMA (fp16 3-term split) fused GEMM+argmin; direct one-hot writeout
// (replaces low-occupancy hipMemsetAsync fill + scatter).
//   dot(x,c) = xh*ch + xh*cl + xl*ch (+ ll dropped, |err| ~ 3e-3)
//   score = csq - 2*dot; argmin via sortable-u32 keys (7 low bits = col idx).
//   Points with top-2 gap < MARGIN re-resolved exactly in fp64.
// Scratch for fp16 operands/partials lives in d_out (fully overwritten by the
// final writeout). nearest[] lives in d_ws.

#define NPTS   32768
#define K_TOTAL 1024
#define D      128
#define MARGIN 0.125f
#define NSTEPS 12

typedef _Float16 half8 __attribute__((ext_vector_type(8)));
typedef float    f32x4 __attribute__((ext_vector_type(4)));

__device__ __forceinline__ unsigned umin_(unsigned a, unsigned b){ return a < b ? a : b; }
__device__ __forceinline__ unsigned umax_(unsigned a, unsigned b){ return a > b ? a : b; }

__device__ __forceinline__ float unsortkey(unsigned k){
    unsigned m = (k >> 31) ? 0x80000000u : 0xFFFFFFFFu;
    return __uint_as_float(k ^ m);
}

__device__ __forceinline__ void gload16(const void* g, void* l){
    __builtin_amdgcn_global_load_lds(
        (const __attribute__((address_space(1))) void*)g,
        (__attribute__((address_space(3))) void*)l, 16, 0, 0);
}

// ---- precompute: standardize X, split to fp16 hi/lo, chunked layout [4][32768][32]
__global__ __launch_bounds__(256) void splitx_kernel(
    const float* __restrict__ X, const float* __restrict__ mean,
    const float* __restrict__ scale,
    _Float16* __restrict__ Xh, _Float16* __restrict__ Xl)
{
    int gid = blockIdx.x * 256 + threadIdx.x;    // 131072
    int c  = gid >> 15;                          // 0..3 (k-chunk)
    int pt = gid & 32767;
    const float4* xs = (const float4*)(X + (size_t)pt * D + c * 32);
    const float4* mp = (const float4*)(mean + c * 32);
    const float4* sp = (const float4*)(scale + c * 32);
    half8 ho[4], llo[4];
    #pragma unroll
    for (int j = 0; j < 8; ++j){
        float4 x = xs[j], m = mp[j], sv = sp[j];
        float f0 = (x.x - m.x) / sv.x, f1 = (x.y - m.y) / sv.y;
        float f2 = (x.z - m.z) / sv.z, f3 = (x.w - m.w) / sv.w;
        _Float16 h0 = (_Float16)f0, h1 = (_Float16)f1, h2 = (_Float16)f2, h3 = (_Float16)f3;
        _Float16 l0 = (_Float16)(f0 - (float)h0), l1 = (_Float16)(f1 - (float)h1);
        _Float16 l2 = (_Float16)(f2 - (float)h2), l3 = (_Float16)(f3 - (float)h3);
        int v = j >> 1, e = (j & 1) * 4;
        ho[v][e] = h0; ho[v][e+1] = h1; ho[v][e+2] = h2; ho[v][e+3] = h3;
        llo[v][e] = l0; llo[v][e+1] = l1; llo[v][e+2] = l2; llo[v][e+3] = l3;
    }
    half8* dh = (half8*)(Xh + ((size_t)c * NPTS + pt) * 32);
    half8* dl = (half8*)(Xl + ((size_t)c * NPTS + pt) * 32);
    #pragma unroll
    for (int v = 0; v < 4; ++v){ dh[v] = ho[v]; dl[v] = llo[v]; }
}

// ---- precompute: centroid split [4][1024][32] + csq fp32 + zero cnt
__global__ __launch_bounds__(256) void splitc_kernel(
    const float* __restrict__ C,
    _Float16* __restrict__ Ch, _Float16* __restrict__ Cl,
    float* __restrict__ csq, int* __restrict__ cnt)
{
    int gid = blockIdx.x * 256 + threadIdx.x;    // 5120
    if (gid == 0) *cnt = 0;
    if (gid < 4096){
        int c = gid >> 10, k = gid & 1023;
        const float4* xs = (const float4*)(C + (size_t)k * D + c * 32);
        half8 ho[4], llo[4];
        #pragma unroll
        for (int j = 0; j < 8; ++j){
            float4 x = xs[j];
            float f0 = x.x, f1 = x.y, f2 = x.z, f3 = x.w;
            _Float16 h0 = (_Float16)f0, h1 = (_Float16)f1, h2 = (_Float16)f2, h3 = (_Float16)f3;
            _Float16 l0 = (_Float16)(f0 - (float)h0), l1 = (_Float16)(f1 - (float)h1);
            _Float16 l2 = (_Float16)(f2 - (float)h2), l3 = (_Float16)(f3 - (float)h3);
            int v = j >> 1, e = (j & 1) * 4;
            ho[v][e] = h0; ho[v][e+1] = h1; ho[v][e+2] = h2; ho[v][e+3] = h3;
            llo[v][e] = l0; llo[v][e+1] = l1; llo[v][e+2] = l2; llo[v][e+3] = l3;
        }
        half8* dh = (half8*)(Ch + ((size_t)c * K_TOTAL + k) * 32);
        half8* dl = (half8*)(Cl + ((size_t)c * K_TOTAL + k) * 32);
        #pragma unroll
        for (int v = 0; v < 4; ++v){ dh[v] = ho[v]; dl[v] = llo[v]; }
    } else if (gid < 5120){
        int k = gid - 4096;
        const float4* cp = (const float4*)(C + (size_t)k * D);
        float s = 0.f;
        #pragma unroll
        for (int j = 0; j < D / 4; ++j){
            float4 v = cp[j];
            s += v.x * v.x; s += v.y * v.y; s += v.z * v.z; s += v.w * v.w;
        }
        csq[k] = s;
    }
}

// ---- fused GEMM (16x16x32 f16 MFMA) + per-tile argmin (min1/min2 keys)
// block: 256 thr = 4 waves (2M x 2N), wave tile 64x64, block tile 128x128.
// grid: (32768/128) * (1024/128) = 256 * 8 = 2048 blocks.
__global__ __launch_bounds__(256, 3) void gemm_kernel(
    const char* __restrict__ scratch, const float* __restrict__ csq,
    unsigned* __restrict__ m1k, unsigned* __restrict__ m2k)
{
    __shared__ __align__(16) char pool[32768];   // A dbuf 2x8K @0, B dbuf 2x8K @16K
    const int tid = threadIdx.x;
    const int bid = blockIdx.x;
    const int nt = bid & 7, mt = bid >> 3;
    const int l = tid & 63, wid = tid >> 6;
    const int wm = wid >> 1, wn = wid & 1;
    const int lr = l & 15, lg = l >> 4;

    const char* Xh = scratch;
    const char* Xl = scratch + (8u << 20);
    const char* Ch = scratch + (16u << 20);
    const char* Cl = scratch + (16u << 20) + (256u << 10);

    f32x4 acc[4][4] = {};

    auto stage = [&](int buf, int s){
        int chunk = s & 3;
        const char* Asrc = ((s < 8) ? Xh : Xl) + ((size_t)chunk * NPTS   + (size_t)mt * 128) * 64;
        const char* Bsrc = (((s >> 2) == 1) ? Cl : Ch) + ((size_t)chunk * K_TOTAL + (size_t)nt * 128) * 64;
        char* Al = pool + buf * 8192;
        char* Bl = pool + 16384 + buf * 8192;
        gload16(Asrc + tid * 16,        Al + wid * 1024);
        gload16(Asrc + 4096 + tid * 16, Al + 4096 + wid * 1024);
        gload16(Bsrc + tid * 16,        Bl + wid * 1024);
        gload16(Bsrc + 4096 + tid * 16, Bl + 4096 + wid * 1024);
    };

    stage(0, 0);
    __syncthreads();
    for (int s = 0; s < NSTEPS; ++s){
        if (s + 1 < NSTEPS) stage((s + 1) & 1, s + 1);
        const _Float16* Ab = (const _Float16*)(pool + (s & 1) * 8192);
        const _Float16* Bb = (const _Float16*)(pool + 16384 + (s & 1) * 8192);
        half8 a[4], b[4];
        #pragma unroll
        for (int mf = 0; mf < 4; ++mf)
            a[mf] = *(const half8*)(Ab + (wm * 64 + mf * 16 + lr) * 32 + lg * 8);
        #pragma unroll
        for (int nf = 0; nf < 4; ++nf)
            b[nf] = *(const half8*)(Bb + (wn * 64 + nf * 16 + lr) * 32 + lg * 8);
        #pragma unroll
        for (int mf = 0; mf < 4; ++mf)
            #pragma unroll
            for (int nf = 0; nf < 4; ++nf)
                acc[mf][nf] = __builtin_amdgcn_mfma_f32_16x16x32_f16(a[mf], b[nf], acc[mf][nf], 0, 0, 0);
        __syncthreads();
    }

    // ---- epilogue: scores -> sortable keys -> per-row top2 via butterfly
    float csqv[4]; unsigned colb[4];
    #pragma unroll
    for (int nf = 0; nf < 4; ++nf){
        int col7 = wn * 64 + nf * 16 + lr;
        csqv[nf] = csq[nt * 128 + col7];
        colb[nf] = (unsigned)col7;
    }
    unsigned* mb = (unsigned*)pool;   // [2 wn][128 rows][2] = 2 KB (pool reused)
    #pragma unroll
    for (int mf = 0; mf < 4; ++mf){
        #pragma unroll
        for (int r = 0; r < 4; ++r){
            unsigned kk[4];
            #pragma unroll
            for (int nf = 0; nf < 4; ++nf){
                float sres = fmaf(-2.0f, acc[mf][nf][r], csqv[nf]);
                unsigned u = __float_as_uint(sres);
                unsigned msk = ((unsigned)((int)u >> 31)) | 0x80000000u;
                kk[nf] = ((u ^ msk) & 0xFFFFFF80u) | colb[nf];
            }
            unsigned lo01 = umin_(kk[0], kk[1]), hi01 = umax_(kk[0], kk[1]);
            unsigned lo23 = umin_(kk[2], kk[3]), hi23 = umax_(kk[2], kk[3]);
            unsigned m1 = umin_(lo01, lo23);
            unsigned m2 = umin_(umax_(lo01, lo23), umin_(hi01, hi23));
            #pragma unroll
            for (int dd = 1; dd <= 8; dd <<= 1){
                unsigned o1 = __shfl_xor(m1, dd, 64);
                unsigned o2 = __shfl_xor(m2, dd, 64);
                unsigned n1 = umin_(m1, o1);
                m2 = umin_(umax_(m1, o1), umin_(m2, o2));
                m1 = n1;
            }
            if (lr == 0){
                int row = wm * 64 + mf * 16 + lg * 4 + r;
                mb[(wn * 128 + row) * 2 + 0] = m1;
                mb[(wn * 128 + row) * 2 + 1] = m2;
            }
        }
    }
    __syncthreads();
    if (tid < 128){
        unsigned a1 = mb[tid * 2],        a2 = mb[tid * 2 + 1];
        unsigned b1 = mb[(128 + tid) * 2], b2 = mb[(128 + tid) * 2 + 1];
        unsigned g1 = umin_(a1, b1);
        unsigned g2 = umin_(umax_(a1, b1), umin_(a2, b2));
        int p = mt * 128 + tid;
        m1k[(size_t)nt * NPTS + p] = g1;
        m2k[(size_t)nt * NPTS + p] = g2;
    }
}

// ---- merge 8 tile-partials per point, flag near-ties
__global__ __launch_bounds__(256) void merge_kernel(
    const unsigned* __restrict__ m1k, const unsigned* __restrict__ m2k,
    int* __restrict__ nearest, int* __restrict__ flags, int* __restrict__ cnt)
{
    int pt = blockIdx.x * 256 + threadIdx.x;     // 32768
    unsigned g1 = 0xFFFFFFFFu, g2 = 0xFFFFFFFFu; int bt = 0;
    #pragma unroll
    for (int t = 0; t < 8; ++t){
        unsigned a = m1k[(size_t)t * NPTS + pt];
        unsigned b = m2k[(size_t)t * NPTS + pt];
        if (a < g1){ g2 = umin_(g1, b); g1 = a; bt = t; }
        else       { g2 = umin_(g2, a); }
    }
    nearest[pt] = bt * 128 + (int)(g1 & 0x7Fu);
    if (unsortkey(g2) - unsortkey(g1) < MARGIN)
        flags[atomicAdd(cnt, 1)] = pt;
}

// ---- fp64 exact re-resolution for near-tie points (rare)
__global__ __launch_bounds__(256) void refine_kernel(
    const float* __restrict__ X, const float* __restrict__ C,
    const float* __restrict__ mean, const float* __restrict__ scale,
    const int* __restrict__ flags, const int* __restrict__ cnt,
    int* __restrict__ nearest)
{
    __shared__ double xs[D];
    __shared__ double bm[256];
    __shared__ int    bk[256];

    const int nf = *cnt;
    for (int f = blockIdx.x; f < nf; f += gridDim.x){
        const int p = flags[f];
        __syncthreads();
        if (threadIdx.x < D){
            int d = threadIdx.x;
            xs[d] = ((double)X[(size_t)p * D + d] - (double)mean[d]) / (double)scale[d];
        }
        __syncthreads();

        double best = 1.0e300; int bestk = K_TOTAL;
        for (int k = threadIdx.x; k < K_TOTAL; k += 256){
            const float* cp = C + (size_t)k * D;
            double s = 0.0;
            for (int d = 0; d < D; ++d){
                double dd = xs[d] - (double)cp[d];
                s += dd * dd;
            }
            if (s < best){ best = s; bestk = k; }
        }
        bm[threadIdx.x] = best; bk[threadIdx.x] = bestk;
        __syncthreads();
        for (int off = 128; off > 0; off >>= 1){
            if (threadIdx.x < off){
                double ob = bm[threadIdx.x + off]; int ok = bk[threadIdx.x + off];
                if (ob < bm[threadIdx.x] ||
                    (ob == bm[threadIdx.x] && ok < bk[threadIdx.x])){
                    bm[threadIdx.x] = ob; bk[threadIdx.x] = ok;
                }
            }
            __syncthreads();
        }
        if (threadIdx.x == 0) nearest[p] = bk[0];
    }
}

// ---- full one-hot writeout: zeros + mask at nearest, coalesced float4 stores
__global__ __launch_bounds__(256) void writeout_kernel(
    const int* __restrict__ nearest, const float* __restrict__ mask,
    float4* __restrict__ out)
{
    const int r0 = blockIdx.x * 8;
    const int j = threadIdx.x;          // float4 index within the row (256 per row)
    const int base = j * 4;
    #pragma unroll
    for (int i = 0; i < 8; ++i) {
        const int row = r0 + i;
        const int nr = nearest[row];
        const float mv = mask[row];
        float4 v = {0.f, 0.f, 0.f, 0.f};
        const int off = nr - base;
        if (off >= 0 && off < 4) ((float*)&v)[off] = mv;
        out[(size_t)row * (K_TOTAL / 4) + j] = v;
    }
}

extern "C" void kernel_launch(void* const* d_in, const int* in_sizes, int n_in,
                              void* d_out, int out_size, void* d_ws, size_t ws_size,
                              hipStream_t stream) {
    const float* X     = (const float*)d_in[0];
    const float* mask  = (const float*)d_in[1];
    const float* C     = (const float*)d_in[2];
    const float* mean  = (const float*)d_in[3];
    const float* scale = (const float*)d_in[4];
    float* out = (float*)d_out;

    // scratch inside d_out (134 MB; we use < 20 MB, all overwritten at the end)
    char* sc = (char*)d_out;
    _Float16* Xh = (_Float16*)(sc);
    _Float16* Xl = (_Float16*)(sc + (8u << 20));
    _Float16* Ch = (_Float16*)(sc + (16u << 20));
    _Float16* Cl = (_Float16*)(sc + (16u << 20) + (256u << 10));
    float*    csq = (float*)(sc + (16u << 20) + (512u << 10));
    unsigned* m1k = (unsigned*)(sc + (17u << 20));
    unsigned* m2k = (unsigned*)(sc + (18u << 20));
    int*      flags = (int*)(sc + (19u << 20));
    int*      cnt   = (int*)(sc + (19u << 20) + (128u << 10));
    int* nearest = (int*)d_ws;   // survives into the writeout

    splitx_kernel<<<512, 256, 0, stream>>>(X, mean, scale, Xh, Xl);
    splitc_kernel<<<20, 256, 0, stream>>>(C, Ch, Cl, csq, cnt);
    gemm_kernel<<<2048, 256, 0, stream>>>(sc, csq, m1k, m2k);
    merge_kernel<<<128, 256, 0, stream>>>(m1k, m2k, nearest, flags, cnt);
    refine_kernel<<<128, 256, 0, stream>>>(X, C, mean, scale, flags, cnt, nearest);
    writeout_kernel<<<NPTS / 8, 256, 0, stream>>>(nearest, mask, (float4*)out);
}

// Round 5
// 137.942 us; speedup vs baseline: 1.1753x; 1.1753x over previous
//
#include <hip/hip_runtime.h>

// ClusterPrior: B=8, N=4096, D=128, K=1024
// Round 5: refine restructured (4 pts/block, C read once per 4 points),
// MARGIN 0.0625 (bound-safe), gemm XCD-aware swizzle, splitx coalescing.
//   dot(x,c) = xh*ch + xh*cl + xl*ch (ll dropped); score = csq - 2*dot.
//   argmin via sortable-u32 keys (7 low bits = col idx); near-ties (gap <
//   MARGIN) re-resolved exactly in fp64.
// Scratch lives in d_out (fully overwritten by writeout). nearest[] in d_ws.

#define NPTS   32768
#define K_TOTAL 1024
#define D      128
#define MARGIN 0.0625f
#define NSTEPS 12
#define RPTS   4

typedef _Float16 half8 __attribute__((ext_vector_type(8)));
typedef float    f32x4 __attribute__((ext_vector_type(4)));

__device__ __forceinline__ unsigned umin_(unsigned a, unsigned b){ return a < b ? a : b; }
__device__ __forceinline__ unsigned umax_(unsigned a, unsigned b){ return a > b ? a : b; }

__device__ __forceinline__ float unsortkey(unsigned k){
    unsigned m = (k >> 31) ? 0x80000000u : 0xFFFFFFFFu;
    return __uint_as_float(k ^ m);
}

__device__ __forceinline__ void gload16(const void* g, void* l){
    __builtin_amdgcn_global_load_lds(
        (const __attribute__((address_space(1))) void*)g,
        (__attribute__((address_space(3))) void*)l, 16, 0, 0);
}

// ---- precompute: standardize X, split to fp16 hi/lo, chunked layout [4][32768][32]
__global__ __launch_bounds__(256) void splitx_kernel(
    const float* __restrict__ X, const float* __restrict__ mean,
    const float* __restrict__ scale,
    _Float16* __restrict__ Xh, _Float16* __restrict__ Xl)
{
    int gid = blockIdx.x * 256 + threadIdx.x;    // 131072
    int pt = gid >> 2;                           // point
    int c  = gid & 3;                            // k-chunk (coalesced loads)
    const float4* xs = (const float4*)(X + (size_t)pt * D + c * 32);
    const float4* mp = (const float4*)(mean + c * 32);
    const float4* sp = (const float4*)(scale + c * 32);
    half8 ho[4], llo[4];
    #pragma unroll
    for (int j = 0; j < 8; ++j){
        float4 x = xs[j], m = mp[j], sv = sp[j];
        float f0 = (x.x - m.x) / sv.x, f1 = (x.y - m.y) / sv.y;
        float f2 = (x.z - m.z) / sv.z, f3 = (x.w - m.w) / sv.w;
        _Float16 h0 = (_Float16)f0, h1 = (_Float16)f1, h2 = (_Float16)f2, h3 = (_Float16)f3;
        _Float16 l0 = (_Float16)(f0 - (float)h0), l1 = (_Float16)(f1 - (float)h1);
        _Float16 l2 = (_Float16)(f2 - (float)h2), l3 = (_Float16)(f3 - (float)h3);
        int v = j >> 1, e = (j & 1) * 4;
        ho[v][e] = h0; ho[v][e+1] = h1; ho[v][e+2] = h2; ho[v][e+3] = h3;
        llo[v][e] = l0; llo[v][e+1] = l1; llo[v][e+2] = l2; llo[v][e+3] = l3;
    }
    half8* dh = (half8*)(Xh + ((size_t)c * NPTS + pt) * 32);
    half8* dl = (half8*)(Xl + ((size_t)c * NPTS + pt) * 32);
    #pragma unroll
    for (int v = 0; v < 4; ++v){ dh[v] = ho[v]; dl[v] = llo[v]; }
}

// ---- precompute: centroid split [4][1024][32] + csq fp32 + zero cnt
__global__ __launch_bounds__(256) void splitc_kernel(
    const float* __restrict__ C,
    _Float16* __restrict__ Ch, _Float16* __restrict__ Cl,
    float* __restrict__ csq, int* __restrict__ cnt)
{
    int gid = blockIdx.x * 256 + threadIdx.x;    // 5120
    if (gid == 0) *cnt = 0;
    if (gid < 4096){
        int k = gid >> 2;
        int c = gid & 3;
        const float4* xs = (const float4*)(C + (size_t)k * D + c * 32);
        half8 ho[4], llo[4];
        #pragma unroll
        for (int j = 0; j < 8; ++j){
            float4 x = xs[j];
            float f0 = x.x, f1 = x.y, f2 = x.z, f3 = x.w;
            _Float16 h0 = (_Float16)f0, h1 = (_Float16)f1, h2 = (_Float16)f2, h3 = (_Float16)f3;
            _Float16 l0 = (_Float16)(f0 - (float)h0), l1 = (_Float16)(f1 - (float)h1);
            _Float16 l2 = (_Float16)(f2 - (float)h2), l3 = (_Float16)(f3 - (float)h3);
            int v = j >> 1, e = (j & 1) * 4;
            ho[v][e] = h0; ho[v][e+1] = h1; ho[v][e+2] = h2; ho[v][e+3] = h3;
            llo[v][e] = l0; llo[v][e+1] = l1; llo[v][e+2] = l2; llo[v][e+3] = l3;
        }
        half8* dh = (half8*)(Ch + ((size_t)c * K_TOTAL + k) * 32);
        half8* dl = (half8*)(Cl + ((size_t)c * K_TOTAL + k) * 32);
        #pragma unroll
        for (int v = 0; v < 4; ++v){ dh[v] = ho[v]; dl[v] = llo[v]; }
    } else if (gid < 5120){
        int k = gid - 4096;
        const float4* cp = (const float4*)(C + (size_t)k * D);
        float s = 0.f;
        #pragma unroll
        for (int j = 0; j < D / 4; ++j){
            float4 v = cp[j];
            s += v.x * v.x; s += v.y * v.y; s += v.z * v.z; s += v.w * v.w;
        }
        csq[k] = s;
    }
}

// ---- fused GEMM (16x16x32 f16 MFMA) + per-tile argmin (min1/min2 keys)
// block: 256 thr = 4 waves (2M x 2N), wave tile 64x64, block tile 128x128.
// grid: 2048; XCD-aware swizzle: all 8 nt-tiles of one mt-panel on one XCD.
__global__ __launch_bounds__(256, 3) void gemm_kernel(
    const char* __restrict__ scratch, const float* __restrict__ csq,
    unsigned* __restrict__ m1k, unsigned* __restrict__ m2k)
{
    __shared__ __align__(16) char pool[32768];   // A dbuf 2x8K @0, B dbuf 2x8K @16K
    const int tid = threadIdx.x;
    const int bid = blockIdx.x;
    // XCD swizzle (8 XCDs, round-robin dispatch): xcd r owns mt in [r*32,(r+1)*32)
    const int r_ = bid & 7, k2 = bid >> 3;
    const int mt = r_ * 32 + (k2 >> 3), nt = k2 & 7;
    const int l = tid & 63, wid = tid >> 6;
    const int wm = wid >> 1, wn = wid & 1;
    const int lr = l & 15, lg = l >> 4;

    const char* Xh = scratch;
    const char* Xl = scratch + (8u << 20);
    const char* Ch = scratch + (16u << 20);
    const char* Cl = scratch + (16u << 20) + (256u << 10);

    f32x4 acc[4][4] = {};

    auto stage = [&](int buf, int s){
        int chunk = s & 3;
        const char* Asrc = ((s < 8) ? Xh : Xl) + ((size_t)chunk * NPTS   + (size_t)mt * 128) * 64;
        const char* Bsrc = (((s >> 2) == 1) ? Cl : Ch) + ((size_t)chunk * K_TOTAL + (size_t)nt * 128) * 64;
        char* Al = pool + buf * 8192;
        char* Bl = pool + 16384 + buf * 8192;
        gload16(Asrc + tid * 16,        Al + wid * 1024);
        gload16(Asrc + 4096 + tid * 16, Al + 4096 + wid * 1024);
        gload16(Bsrc + tid * 16,        Bl + wid * 1024);
        gload16(Bsrc + 4096 + tid * 16, Bl + 4096 + wid * 1024);
    };

    stage(0, 0);
    __syncthreads();
    for (int s = 0; s < NSTEPS; ++s){
        if (s + 1 < NSTEPS) stage((s + 1) & 1, s + 1);
        const _Float16* Ab = (const _Float16*)(pool + (s & 1) * 8192);
        const _Float16* Bb = (const _Float16*)(pool + 16384 + (s & 1) * 8192);
        half8 a[4], b[4];
        #pragma unroll
        for (int mf = 0; mf < 4; ++mf)
            a[mf] = *(const half8*)(Ab + (wm * 64 + mf * 16 + lr) * 32 + lg * 8);
        #pragma unroll
        for (int nf = 0; nf < 4; ++nf)
            b[nf] = *(const half8*)(Bb + (wn * 64 + nf * 16 + lr) * 32 + lg * 8);
        #pragma unroll
        for (int mf = 0; mf < 4; ++mf)
            #pragma unroll
            for (int nf = 0; nf < 4; ++nf)
                acc[mf][nf] = __builtin_amdgcn_mfma_f32_16x16x32_f16(a[mf], b[nf], acc[mf][nf], 0, 0, 0);
        __syncthreads();
    }

    // ---- epilogue: scores -> sortable keys -> per-row top2 via butterfly
    float csqv[4]; unsigned colb[4];
    #pragma unroll
    for (int nf = 0; nf < 4; ++nf){
        int col7 = wn * 64 + nf * 16 + lr;
        csqv[nf] = csq[nt * 128 + col7];
        colb[nf] = (unsigned)col7;
    }
    unsigned* mb = (unsigned*)pool;   // [2 wn][128 rows][2] = 2 KB (pool reused)
    #pragma unroll
    for (int mf = 0; mf < 4; ++mf){
        #pragma unroll
        for (int r = 0; r < 4; ++r){
            unsigned kk[4];
            #pragma unroll
            for (int nf = 0; nf < 4; ++nf){
                float sres = fmaf(-2.0f, acc[mf][nf][r], csqv[nf]);
                unsigned u = __float_as_uint(sres);
                unsigned msk = ((unsigned)((int)u >> 31)) | 0x80000000u;
                kk[nf] = ((u ^ msk) & 0xFFFFFF80u) | colb[nf];
            }
            unsigned lo01 = umin_(kk[0], kk[1]), hi01 = umax_(kk[0], kk[1]);
            unsigned lo23 = umin_(kk[2], kk[3]), hi23 = umax_(kk[2], kk[3]);
            unsigned m1 = umin_(lo01, lo23);
            unsigned m2 = umin_(umax_(lo01, lo23), umin_(hi01, hi23));
            #pragma unroll
            for (int dd = 1; dd <= 8; dd <<= 1){
                unsigned o1 = __shfl_xor(m1, dd, 64);
                unsigned o2 = __shfl_xor(m2, dd, 64);
                unsigned n1 = umin_(m1, o1);
                m2 = umin_(umax_(m1, o1), umin_(m2, o2));
                m1 = n1;
            }
            if (lr == 0){
                int row = wm * 64 + mf * 16 + lg * 4 + r;
                mb[(wn * 128 + row) * 2 + 0] = m1;
                mb[(wn * 128 + row) * 2 + 1] = m2;
            }
        }
    }
    __syncthreads();
    if (tid < 128){
        unsigned a1 = mb[tid * 2],        a2 = mb[tid * 2 + 1];
        unsigned b1 = mb[(128 + tid) * 2], b2 = mb[(128 + tid) * 2 + 1];
        unsigned g1 = umin_(a1, b1);
        unsigned g2 = umin_(umax_(a1, b1), umin_(a2, b2));
        int p = mt * 128 + tid;
        m1k[(size_t)nt * NPTS + p] = g1;
        m2k[(size_t)nt * NPTS + p] = g2;
    }
}

// ---- merge 8 tile-partials per point, flag near-ties
__global__ __launch_bounds__(256) void merge_kernel(
    const unsigned* __restrict__ m1k, const unsigned* __restrict__ m2k,
    int* __restrict__ nearest, int* __restrict__ flags, int* __restrict__ cnt)
{
    int pt = blockIdx.x * 256 + threadIdx.x;     // 32768
    unsigned g1 = 0xFFFFFFFFu, g2 = 0xFFFFFFFFu; int bt = 0;
    #pragma unroll
    for (int t = 0; t < 8; ++t){
        unsigned a = m1k[(size_t)t * NPTS + pt];
        unsigned b = m2k[(size_t)t * NPTS + pt];
        if (a < g1){ g2 = umin_(g1, b); g1 = a; bt = t; }
        else       { g2 = umin_(g2, a); }
    }
    nearest[pt] = bt * 128 + (int)(g1 & 0x7Fu);
    if (unsortkey(g2) - unsortkey(g1) < MARGIN)
        flags[atomicAdd(cnt, 1)] = pt;
}

// ---- fp64 exact re-resolution for near-tie points: RPTS points per block,
// C read ONCE per RPTS points (was once per point).
__global__ __launch_bounds__(256) void refine_kernel(
    const float* __restrict__ X, const float* __restrict__ C,
    const float* __restrict__ mean, const float* __restrict__ scale,
    const int* __restrict__ flags, const int* __restrict__ cnt,
    int* __restrict__ nearest)
{
    __shared__ double xs[RPTS][D];
    __shared__ double bm[256];
    __shared__ int    bk[256];

    const int nf = *cnt;
    for (int base = blockIdx.x * RPTS; base < nf; base += gridDim.x * RPTS){
        const int np = (nf - base < RPTS) ? (nf - base) : RPTS;
        __syncthreads();
        for (int idx = threadIdx.x; idx < np * D; idx += 256){
            int pp = idx >> 7, d = idx & 127;
            int p = flags[base + pp];
            xs[pp][d] = ((double)X[(size_t)p * D + d] - (double)mean[d]) / (double)scale[d];
        }
        __syncthreads();

        double best[RPTS]; int bestk[RPTS];
        #pragma unroll
        for (int pp = 0; pp < RPTS; ++pp){ best[pp] = 1.0e300; bestk[pp] = K_TOTAL; }

        for (int k = threadIdx.x; k < K_TOTAL; k += 256){
            const float* cp = C + (size_t)k * D;
            double s[RPTS] = {0.0, 0.0, 0.0, 0.0};
            for (int d = 0; d < D; d += 4){
                float4 cv = *(const float4*)(cp + d);
                double c0 = cv.x, c1 = cv.y, c2 = cv.z, c3 = cv.w;
                #pragma unroll
                for (int pp = 0; pp < RPTS; ++pp){
                    double d0 = xs[pp][d]     - c0;
                    double d1 = xs[pp][d + 1] - c1;
                    double d2 = xs[pp][d + 2] - c2;
                    double d3 = xs[pp][d + 3] - c3;
                    s[pp] += d0 * d0 + d1 * d1 + d2 * d2 + d3 * d3;
                }
            }
            #pragma unroll
            for (int pp = 0; pp < RPTS; ++pp)
                if (s[pp] < best[pp]){ best[pp] = s[pp]; bestk[pp] = k; }
        }

        for (int pp = 0; pp < np; ++pp){
            __syncthreads();
            bm[threadIdx.x] = best[pp]; bk[threadIdx.x] = bestk[pp];
            __syncthreads();
            for (int off = 128; off > 0; off >>= 1){
                if (threadIdx.x < off){
                    double ob = bm[threadIdx.x + off]; int ok = bk[threadIdx.x + off];
                    if (ob < bm[threadIdx.x] ||
                        (ob == bm[threadIdx.x] && ok < bk[threadIdx.x])){
                        bm[threadIdx.x] = ob; bk[threadIdx.x] = ok;
                    }
                }
                __syncthreads();
            }
            if (threadIdx.x == 0) nearest[flags[base + pp]] = bk[0];
        }
    }
}

// ---- full one-hot writeout: zeros + mask at nearest, coalesced float4 stores
__global__ __launch_bounds__(256) void writeout_kernel(
    const int* __restrict__ nearest, const float* __restrict__ mask,
    float4* __restrict__ out)
{
    const int r0 = blockIdx.x * 8;
    const int j = threadIdx.x;          // float4 index within the row (256 per row)
    const int base = j * 4;
    #pragma unroll
    for (int i = 0; i < 8; ++i) {
        const int row = r0 + i;
        const int nr = nearest[row];
        const float mv = mask[row];
        float4 v = {0.f, 0.f, 0.f, 0.f};
        const int off = nr - base;
        if (off >= 0 && off < 4) ((float*)&v)[off] = mv;
        out[(size_t)row * (K_TOTAL / 4) + j] = v;
    }
}

extern "C" void kernel_launch(void* const* d_in, const int* in_sizes, int n_in,
                              void* d_out, int out_size, void* d_ws, size_t ws_size,
                              hipStream_t stream) {
    const float* X     = (const float*)d_in[0];
    const float* mask  = (const float*)d_in[1];
    const float* C     = (const float*)d_in[2];
    const float* mean  = (const float*)d_in[3];
    const float* scale = (const float*)d_in[4];
    float* out = (float*)d_out;

    // scratch inside d_out (134 MB; we use < 20 MB, all overwritten at the end)
    char* sc = (char*)d_out;
    _Float16* Xh = (_Float16*)(sc);
    _Float16* Xl = (_Float16*)(sc + (8u << 20));
    _Float16* Ch = (_Float16*)(sc + (16u << 20));
    _Float16* Cl = (_Float16*)(sc + (16u << 20) + (256u << 10));
    float*    csq = (float*)(sc + (16u << 20) + (512u << 10));
    unsigned* m1k = (unsigned*)(sc + (17u << 20));
    unsigned* m2k = (unsigned*)(sc + (18u << 20));
    int*      flags = (int*)(sc + (19u << 20));
    int*      cnt   = (int*)(sc + (19u << 20) + (128u << 10));
    int* nearest = (int*)d_ws;   // survives into the writeout

    splitx_kernel<<<512, 256, 0, stream>>>(X, mean, scale, Xh, Xl);
    splitc_kernel<<<20, 256, 0, stream>>>(C, Ch, Cl, csq, cnt);
    gemm_kernel<<<2048, 256, 0, stream>>>(sc, csq, m1k, m2k);
    merge_kernel<<<128, 256, 0, stream>>>(m1k, m2k, nearest, flags, cnt);
    refine_kernel<<<512, 256, 0, stream>>>(X, C, mean, scale, flags, cnt, nearest);
    writeout_kernel<<<NPTS / 8, 256, 0, stream>>>(nearest, mask, (float4*)out);
}

// Round 6
// 131.423 us; speedup vs baseline: 1.2336x; 1.0496x over previous
//
#include <hip/hip_runtime.h>

// ClusterPrior: B=8, N=4096, D=128, K=1024
// Round 6: drop the xh*cl GEMM term (K=384 -> 256, -33% MFMA work);
// MARGIN back to 0.125 (dropped-term RMS ~7e-3, 18x safety; near-ties
// re-resolved exactly in fp64 so argmin stays exact).
//   dot(x,c) ~= xh*ch + xl*ch; score = csq - 2*dot.
//   argmin via sortable-u32 keys (7 low bits = col idx).
// Scratch lives in d_out (fully overwritten by writeout). nearest[] in d_ws.

#define NPTS   32768
#define K_TOTAL 1024
#define D      128
#define MARGIN 0.125f
#define NSTEPS 8
#define RPTS   4

typedef _Float16 half8 __attribute__((ext_vector_type(8)));
typedef float    f32x4 __attribute__((ext_vector_type(4)));

__device__ __forceinline__ unsigned umin_(unsigned a, unsigned b){ return a < b ? a : b; }
__device__ __forceinline__ unsigned umax_(unsigned a, unsigned b){ return a > b ? a : b; }

__device__ __forceinline__ float unsortkey(unsigned k){
    unsigned m = (k >> 31) ? 0x80000000u : 0xFFFFFFFFu;
    return __uint_as_float(k ^ m);
}

__device__ __forceinline__ void gload16(const void* g, void* l){
    __builtin_amdgcn_global_load_lds(
        (const __attribute__((address_space(1))) void*)g,
        (__attribute__((address_space(3))) void*)l, 16, 0, 0);
}

// ---- precompute: standardize X, split to fp16 hi/lo, chunked layout [4][32768][32]
__global__ __launch_bounds__(256) void splitx_kernel(
    const float* __restrict__ X, const float* __restrict__ mean,
    const float* __restrict__ scale,
    _Float16* __restrict__ Xh, _Float16* __restrict__ Xl)
{
    int gid = blockIdx.x * 256 + threadIdx.x;    // 131072
    int pt = gid >> 2;                           // point
    int c  = gid & 3;                            // k-chunk (coalesced loads)
    const float4* xs = (const float4*)(X + (size_t)pt * D + c * 32);
    const float4* mp = (const float4*)(mean + c * 32);
    const float4* sp = (const float4*)(scale + c * 32);
    half8 ho[4], llo[4];
    #pragma unroll
    for (int j = 0; j < 8; ++j){
        float4 x = xs[j], m = mp[j], sv = sp[j];
        float f0 = (x.x - m.x) / sv.x, f1 = (x.y - m.y) / sv.y;
        float f2 = (x.z - m.z) / sv.z, f3 = (x.w - m.w) / sv.w;
        _Float16 h0 = (_Float16)f0, h1 = (_Float16)f1, h2 = (_Float16)f2, h3 = (_Float16)f3;
        _Float16 l0 = (_Float16)(f0 - (float)h0), l1 = (_Float16)(f1 - (float)h1);
        _Float16 l2 = (_Float16)(f2 - (float)h2), l3 = (_Float16)(f3 - (float)h3);
        int v = j >> 1, e = (j & 1) * 4;
        ho[v][e] = h0; ho[v][e+1] = h1; ho[v][e+2] = h2; ho[v][e+3] = h3;
        llo[v][e] = l0; llo[v][e+1] = l1; llo[v][e+2] = l2; llo[v][e+3] = l3;
    }
    half8* dh = (half8*)(Xh + ((size_t)c * NPTS + pt) * 32);
    half8* dl = (half8*)(Xl + ((size_t)c * NPTS + pt) * 32);
    #pragma unroll
    for (int v = 0; v < 4; ++v){ dh[v] = ho[v]; dl[v] = llo[v]; }
}

// ---- precompute: centroid fp16 [4][1024][32] + csq fp32 + zero cnt
__global__ __launch_bounds__(256) void splitc_kernel(
    const float* __restrict__ C,
    _Float16* __restrict__ Ch,
    float* __restrict__ csq, int* __restrict__ cnt)
{
    int gid = blockIdx.x * 256 + threadIdx.x;    // 5120
    if (gid == 0) *cnt = 0;
    if (gid < 4096){
        int k = gid >> 2;
        int c = gid & 3;
        const float4* xs = (const float4*)(C + (size_t)k * D + c * 32);
        half8 ho[4];
        #pragma unroll
        for (int j = 0; j < 8; ++j){
            float4 x = xs[j];
            int v = j >> 1, e = (j & 1) * 4;
            ho[v][e]   = (_Float16)x.x; ho[v][e+1] = (_Float16)x.y;
            ho[v][e+2] = (_Float16)x.z; ho[v][e+3] = (_Float16)x.w;
        }
        half8* dh = (half8*)(Ch + ((size_t)c * K_TOTAL + k) * 32);
        #pragma unroll
        for (int v = 0; v < 4; ++v) dh[v] = ho[v];
    } else if (gid < 5120){
        int k = gid - 4096;
        const float4* cp = (const float4*)(C + (size_t)k * D);
        float s = 0.f;
        #pragma unroll
        for (int j = 0; j < D / 4; ++j){
            float4 v = cp[j];
            s += v.x * v.x; s += v.y * v.y; s += v.z * v.z; s += v.w * v.w;
        }
        csq[k] = s;
    }
}

// ---- fused GEMM (16x16x32 f16 MFMA) + per-tile argmin (min1/min2 keys)
// A = [xh | xl] (K=256), B = [ch | ch]. block: 256 thr = 4 waves (2M x 2N),
// wave tile 64x64, block tile 128x128. grid 2048; XCD-aware swizzle.
__global__ __launch_bounds__(256, 3) void gemm_kernel(
    const char* __restrict__ scratch, const float* __restrict__ csq,
    unsigned* __restrict__ m1k, unsigned* __restrict__ m2k)
{
    __shared__ __align__(16) char pool[32768];   // A dbuf 2x8K @0, B dbuf 2x8K @16K
    const int tid = threadIdx.x;
    const int bid = blockIdx.x;
    // XCD swizzle (8 XCDs, round-robin dispatch): xcd r owns mt in [r*32,(r+1)*32)
    const int r_ = bid & 7, k2 = bid >> 3;
    const int mt = r_ * 32 + (k2 >> 3), nt = k2 & 7;
    const int l = tid & 63, wid = tid >> 6;
    const int wm = wid >> 1, wn = wid & 1;
    const int lr = l & 15, lg = l >> 4;

    const char* Xh = scratch;
    const char* Xl = scratch + (8u << 20);
    const char* Ch = scratch + (16u << 20);

    f32x4 acc[4][4] = {};

    auto stage = [&](int buf, int s){
        int chunk = s & 3;
        const char* Asrc = ((s < 4) ? Xh : Xl) + ((size_t)chunk * NPTS   + (size_t)mt * 128) * 64;
        const char* Bsrc = Ch + ((size_t)chunk * K_TOTAL + (size_t)nt * 128) * 64;
        char* Al = pool + buf * 8192;
        char* Bl = pool + 16384 + buf * 8192;
        gload16(Asrc + tid * 16,        Al + wid * 1024);
        gload16(Asrc + 4096 + tid * 16, Al + 4096 + wid * 1024);
        gload16(Bsrc + tid * 16,        Bl + wid * 1024);
        gload16(Bsrc + 4096 + tid * 16, Bl + 4096 + wid * 1024);
    };

    stage(0, 0);
    __syncthreads();
    for (int s = 0; s < NSTEPS; ++s){
        if (s + 1 < NSTEPS) stage((s + 1) & 1, s + 1);
        const _Float16* Ab = (const _Float16*)(pool + (s & 1) * 8192);
        const _Float16* Bb = (const _Float16*)(pool + 16384 + (s & 1) * 8192);
        half8 a[4], b[4];
        #pragma unroll
        for (int mf = 0; mf < 4; ++mf)
            a[mf] = *(const half8*)(Ab + (wm * 64 + mf * 16 + lr) * 32 + lg * 8);
        #pragma unroll
        for (int nf = 0; nf < 4; ++nf)
            b[nf] = *(const half8*)(Bb + (wn * 64 + nf * 16 + lr) * 32 + lg * 8);
        #pragma unroll
        for (int mf = 0; mf < 4; ++mf)
            #pragma unroll
            for (int nf = 0; nf < 4; ++nf)
                acc[mf][nf] = __builtin_amdgcn_mfma_f32_16x16x32_f16(a[mf], b[nf], acc[mf][nf], 0, 0, 0);
        __syncthreads();
    }

    // ---- epilogue: scores -> sortable keys -> per-row top2 via butterfly
    float csqv[4]; unsigned colb[4];
    #pragma unroll
    for (int nf = 0; nf < 4; ++nf){
        int col7 = wn * 64 + nf * 16 + lr;
        csqv[nf] = csq[nt * 128 + col7];
        colb[nf] = (unsigned)col7;
    }
    unsigned* mb = (unsigned*)pool;   // [2 wn][128 rows][2] = 2 KB (pool reused)
    #pragma unroll
    for (int mf = 0; mf < 4; ++mf){
        #pragma unroll
        for (int r = 0; r < 4; ++r){
            unsigned kk[4];
            #pragma unroll
            for (int nf = 0; nf < 4; ++nf){
                float sres = fmaf(-2.0f, acc[mf][nf][r], csqv[nf]);
                unsigned u = __float_as_uint(sres);
                unsigned msk = ((unsigned)((int)u >> 31)) | 0x80000000u;
                kk[nf] = ((u ^ msk) & 0xFFFFFF80u) | colb[nf];
            }
            unsigned lo01 = umin_(kk[0], kk[1]), hi01 = umax_(kk[0], kk[1]);
            unsigned lo23 = umin_(kk[2], kk[3]), hi23 = umax_(kk[2], kk[3]);
            unsigned m1 = umin_(lo01, lo23);
            unsigned m2 = umin_(umax_(lo01, lo23), umin_(hi01, hi23));
            #pragma unroll
            for (int dd = 1; dd <= 8; dd <<= 1){
                unsigned o1 = __shfl_xor(m1, dd, 64);
                unsigned o2 = __shfl_xor(m2, dd, 64);
                unsigned n1 = umin_(m1, o1);
                m2 = umin_(umax_(m1, o1), umin_(m2, o2));
                m1 = n1;
            }
            if (lr == 0){
                int row = wm * 64 + mf * 16 + lg * 4 + r;
                mb[(wn * 128 + row) * 2 + 0] = m1;
                mb[(wn * 128 + row) * 2 + 1] = m2;
            }
        }
    }
    __syncthreads();
    if (tid < 128){
        unsigned a1 = mb[tid * 2],        a2 = mb[tid * 2 + 1];
        unsigned b1 = mb[(128 + tid) * 2], b2 = mb[(128 + tid) * 2 + 1];
        unsigned g1 = umin_(a1, b1);
        unsigned g2 = umin_(umax_(a1, b1), umin_(a2, b2));
        int p = mt * 128 + tid;
        m1k[(size_t)nt * NPTS + p] = g1;
        m2k[(size_t)nt * NPTS + p] = g2;
    }
}

// ---- merge 8 tile-partials per point, flag near-ties
__global__ __launch_bounds__(256) void merge_kernel(
    const unsigned* __restrict__ m1k, const unsigned* __restrict__ m2k,
    int* __restrict__ nearest, int* __restrict__ flags, int* __restrict__ cnt)
{
    int pt = blockIdx.x * 256 + threadIdx.x;     // 32768
    unsigned g1 = 0xFFFFFFFFu, g2 = 0xFFFFFFFFu; int bt = 0;
    #pragma unroll
    for (int t = 0; t < 8; ++t){
        unsigned a = m1k[(size_t)t * NPTS + pt];
        unsigned b = m2k[(size_t)t * NPTS + pt];
        if (a < g1){ g2 = umin_(g1, b); g1 = a; bt = t; }
        else       { g2 = umin_(g2, a); }
    }
    nearest[pt] = bt * 128 + (int)(g1 & 0x7Fu);
    if (unsortkey(g2) - unsortkey(g1) < MARGIN)
        flags[atomicAdd(cnt, 1)] = pt;
}

// ---- fp64 exact re-resolution for near-tie points: RPTS points per block,
// C read ONCE per RPTS points.
__global__ __launch_bounds__(256) void refine_kernel(
    const float* __restrict__ X, const float* __restrict__ C,
    const float* __restrict__ mean, const float* __restrict__ scale,
    const int* __restrict__ flags, const int* __restrict__ cnt,
    int* __restrict__ nearest)
{
    __shared__ double xs[RPTS][D];
    __shared__ double bm[256];
    __shared__ int    bk[256];

    const int nf = *cnt;
    for (int base = blockIdx.x * RPTS; base < nf; base += gridDim.x * RPTS){
        const int np = (nf - base < RPTS) ? (nf - base) : RPTS;
        __syncthreads();
        for (int idx = threadIdx.x; idx < np * D; idx += 256){
            int pp = idx >> 7, d = idx & 127;
            int p = flags[base + pp];
            xs[pp][d] = ((double)X[(size_t)p * D + d] - (double)mean[d]) / (double)scale[d];
        }
        __syncthreads();

        double best[RPTS]; int bestk[RPTS];
        #pragma unroll
        for (int pp = 0; pp < RPTS; ++pp){ best[pp] = 1.0e300; bestk[pp] = K_TOTAL; }

        for (int k = threadIdx.x; k < K_TOTAL; k += 256){
            const float* cp = C + (size_t)k * D;
            double s[RPTS] = {0.0, 0.0, 0.0, 0.0};
            for (int d = 0; d < D; d += 4){
                float4 cv = *(const float4*)(cp + d);
                double c0 = cv.x, c1 = cv.y, c2 = cv.z, c3 = cv.w;
                #pragma unroll
                for (int pp = 0; pp < RPTS; ++pp){
                    double d0 = xs[pp][d]     - c0;
                    double d1 = xs[pp][d + 1] - c1;
                    double d2 = xs[pp][d + 2] - c2;
                    double d3 = xs[pp][d + 3] - c3;
                    s[pp] += d0 * d0 + d1 * d1 + d2 * d2 + d3 * d3;
                }
            }
            #pragma unroll
            for (int pp = 0; pp < RPTS; ++pp)
                if (s[pp] < best[pp]){ best[pp] = s[pp]; bestk[pp] = k; }
        }

        for (int pp = 0; pp < np; ++pp){
            __syncthreads();
            bm[threadIdx.x] = best[pp]; bk[threadIdx.x] = bestk[pp];
            __syncthreads();
            for (int off = 128; off > 0; off >>= 1){
                if (threadIdx.x < off){
                    double ob = bm[threadIdx.x + off]; int ok = bk[threadIdx.x + off];
                    if (ob < bm[threadIdx.x] ||
                        (ob == bm[threadIdx.x] && ok < bk[threadIdx.x])){
                        bm[threadIdx.x] = ob; bk[threadIdx.x] = ok;
                    }
                }
                __syncthreads();
            }
            if (threadIdx.x == 0) nearest[flags[base + pp]] = bk[0];
        }
    }
}

// ---- full one-hot writeout: zeros + mask at nearest, coalesced float4 stores
__global__ __launch_bounds__(256) void writeout_kernel(
    const int* __restrict__ nearest, const float* __restrict__ mask,
    float4* __restrict__ out)
{
    const int r0 = blockIdx.x * 8;
    const int j = threadIdx.x;          // float4 index within the row (256 per row)
    const int base = j * 4;
    #pragma unroll
    for (int i = 0; i < 8; ++i) {
        const int row = r0 + i;
        const int nr = nearest[row];
        const float mv = mask[row];
        float4 v = {0.f, 0.f, 0.f, 0.f};
        const int off = nr - base;
        if (off >= 0 && off < 4) ((float*)&v)[off] = mv;
        out[(size_t)row * (K_TOTAL / 4) + j] = v;
    }
}

extern "C" void kernel_launch(void* const* d_in, const int* in_sizes, int n_in,
                              void* d_out, int out_size, void* d_ws, size_t ws_size,
                              hipStream_t stream) {
    const float* X     = (const float*)d_in[0];
    const float* mask  = (const float*)d_in[1];
    const float* C     = (const float*)d_in[2];
    const float* mean  = (const float*)d_in[3];
    const float* scale = (const float*)d_in[4];
    float* out = (float*)d_out;

    // scratch inside d_out (134 MB; we use < 20 MB, all overwritten at the end)
    char* sc = (char*)d_out;
    _Float16* Xh = (_Float16*)(sc);
    _Float16* Xl = (_Float16*)(sc + (8u << 20));
    _Float16* Ch = (_Float16*)(sc + (16u << 20));
    float*    csq = (float*)(sc + (16u << 20) + (512u << 10));
    unsigned* m1k = (unsigned*)(sc + (17u << 20));
    unsigned* m2k = (unsigned*)(sc + (18u << 20));
    int*      flags = (int*)(sc + (19u << 20));
    int*      cnt   = (int*)(sc + (19u << 20) + (128u << 10));
    int* nearest = (int*)d_ws;   // survives into the writeout

    splitx_kernel<<<512, 256, 0, stream>>>(X, mean, scale, Xh, Xl);
    splitc_kernel<<<20, 256, 0, stream>>>(C, Ch, csq, cnt);
    gemm_kernel<<<2048, 256, 0, stream>>>(sc, csq, m1k, m2k);
    merge_kernel<<<128, 256, 0, stream>>>(m1k, m2k, nearest, flags, cnt);
    refine_kernel<<<512, 256, 0, stream>>>(X, C, mean, scale, flags, cnt, nearest);
    writeout_kernel<<<NPTS / 8, 256, 0, stream>>>(nearest, mask, (float4*)out);
}

// Round 7
// 118.917 us; speedup vs baseline: 1.3633x; 1.1052x over previous
//
#include <hip/hip_runtime.h>

// ClusterPrior: B=8, N=4096, D=128, K=1024
// Round 7: gemm re-tiled 128x256 (1024 blocks, 2x MFMA per barrier, A-panel
// XCD-grouped), splitc fused into splitx. Budget model: ~77us harness fill is
// a fixed tax inside dur_us; controllable ~54us = splits 6 + gemm 19 + merge
// 1.5 + refine 6 + writeout 20 (HBM floor).
//   dot(x,c) ~= xh*ch + xl*ch (xh*cl dropped, RMS ~7e-3); score = csq - 2*dot.
//   argmin via sortable-u32 keys (8 low bits = col in 256-tile); near-ties
//   (gap < MARGIN) re-resolved exactly in fp64.
// Scratch lives in d_out (fully overwritten by writeout). nearest[] in d_ws.

#define NPTS   32768
#define K_TOTAL 1024
#define D      128
#define MARGIN 0.125f
#define NSTEPS 8
#define RPTS   4

typedef _Float16 half8 __attribute__((ext_vector_type(8)));
typedef float    f32x4 __attribute__((ext_vector_type(4)));

__device__ __forceinline__ unsigned umin_(unsigned a, unsigned b){ return a < b ? a : b; }
__device__ __forceinline__ unsigned umax_(unsigned a, unsigned b){ return a > b ? a : b; }

__device__ __forceinline__ float unsortkey(unsigned k){
    unsigned m = (k >> 31) ? 0x80000000u : 0xFFFFFFFFu;
    return __uint_as_float(k ^ m);
}

__device__ __forceinline__ void gload16(const void* g, void* l){
    __builtin_amdgcn_global_load_lds(
        (const __attribute__((address_space(1))) void*)g,
        (__attribute__((address_space(3))) void*)l, 16, 0, 0);
}

// ---- precompute (fused): blocks <512: standardize+split X -> [4][32768][32];
// blocks >=512: centroid fp16 [4][1024][32] + csq + zero cnt.
__global__ __launch_bounds__(256) void split_kernel(
    const float* __restrict__ X, const float* __restrict__ mean,
    const float* __restrict__ scale, const float* __restrict__ C,
    _Float16* __restrict__ Xh, _Float16* __restrict__ Xl,
    _Float16* __restrict__ Ch, float* __restrict__ csq, int* __restrict__ cnt)
{
    if (blockIdx.x < 512){
        int gid = blockIdx.x * 256 + threadIdx.x;    // 131072
        int pt = gid >> 2;                           // point
        int c  = gid & 3;                            // k-chunk
        const float4* xs = (const float4*)(X + (size_t)pt * D + c * 32);
        const float4* mp = (const float4*)(mean + c * 32);
        const float4* sp = (const float4*)(scale + c * 32);
        half8 ho[4], llo[4];
        #pragma unroll
        for (int j = 0; j < 8; ++j){
            float4 x = xs[j], m = mp[j], sv = sp[j];
            float f0 = (x.x - m.x) / sv.x, f1 = (x.y - m.y) / sv.y;
            float f2 = (x.z - m.z) / sv.z, f3 = (x.w - m.w) / sv.w;
            _Float16 h0 = (_Float16)f0, h1 = (_Float16)f1, h2 = (_Float16)f2, h3 = (_Float16)f3;
            _Float16 l0 = (_Float16)(f0 - (float)h0), l1 = (_Float16)(f1 - (float)h1);
            _Float16 l2 = (_Float16)(f2 - (float)h2), l3 = (_Float16)(f3 - (float)h3);
            int v = j >> 1, e = (j & 1) * 4;
            ho[v][e] = h0; ho[v][e+1] = h1; ho[v][e+2] = h2; ho[v][e+3] = h3;
            llo[v][e] = l0; llo[v][e+1] = l1; llo[v][e+2] = l2; llo[v][e+3] = l3;
        }
        half8* dh = (half8*)(Xh + ((size_t)c * NPTS + pt) * 32);
        half8* dl = (half8*)(Xl + ((size_t)c * NPTS + pt) * 32);
        #pragma unroll
        for (int v = 0; v < 4; ++v){ dh[v] = ho[v]; dl[v] = llo[v]; }
    } else {
        int gid = (blockIdx.x - 512) * 256 + threadIdx.x;    // 5120
        if (gid == 0) *cnt = 0;
        if (gid < 4096){
            int k = gid >> 2;
            int c = gid & 3;
            const float4* xs = (const float4*)(C + (size_t)k * D + c * 32);
            half8 ho[4];
            #pragma unroll
            for (int j = 0; j < 8; ++j){
                float4 x = xs[j];
                int v = j >> 1, e = (j & 1) * 4;
                ho[v][e]   = (_Float16)x.x; ho[v][e+1] = (_Float16)x.y;
                ho[v][e+2] = (_Float16)x.z; ho[v][e+3] = (_Float16)x.w;
            }
            half8* dh = (half8*)(Ch + ((size_t)c * K_TOTAL + k) * 32);
            #pragma unroll
            for (int v = 0; v < 4; ++v) dh[v] = ho[v];
        } else if (gid < 5120){
            int k = gid - 4096;
            const float4* cp = (const float4*)(C + (size_t)k * D);
            float s = 0.f;
            #pragma unroll
            for (int j = 0; j < D / 4; ++j){
                float4 v = cp[j];
                s += v.x * v.x; s += v.y * v.y; s += v.z * v.z; s += v.w * v.w;
            }
            csq[k] = s;
        }
    }
}

// ---- fused GEMM (16x16x32 f16 MFMA) + per-tile argmin (min1/min2 keys)
// A = [xh | xl] (K=256), B = [ch | ch]. Block tile 128 pts x 256 cols;
// 4 waves (2M x 2N), wave tile 64x128 (acc 4x8 f32x4). grid 1024;
// XCD swizzle groups all 4 nt-tiles of an mt-panel on one XCD.
__global__ __launch_bounds__(256, 2) void gemm_kernel(
    const char* __restrict__ scratch, const float* __restrict__ csq,
    unsigned* __restrict__ m1k, unsigned* __restrict__ m2k)
{
    __shared__ __align__(16) char pool[49152];   // A dbuf 2x8K @0, B dbuf 2x16K @16K
    const int tid = threadIdx.x;
    const int bid = blockIdx.x;
    // 8 XCDs round-robin: xcd r owns mt in [r*32,(r+1)*32); nt fastest inside.
    const int r_ = bid & 7, k2 = bid >> 3;          // k2 in [0,128)
    const int mt = r_ * 32 + (k2 >> 2), nt = k2 & 3;
    const int l = tid & 63, wid = tid >> 6;
    const int wm = wid >> 1, wn = wid & 1;
    const int lr = l & 15, lg = l >> 4;

    const char* Xh = scratch;
    const char* Xl = scratch + (8u << 20);
    const char* Ch = scratch + (16u << 20);

    f32x4 acc[4][8] = {};

    auto stage = [&](int buf, int s){
        int chunk = s & 3;
        const char* Asrc = ((s < 4) ? Xh : Xl) + ((size_t)chunk * NPTS   + (size_t)mt * 128) * 64;
        const char* Bsrc = Ch + ((size_t)chunk * K_TOTAL + (size_t)nt * 256) * 64;
        char* Al = pool + buf * 8192;
        char* Bl = pool + 16384 + buf * 16384;
        gload16(Asrc + tid * 16,         Al + wid * 1024);
        gload16(Asrc + 4096 + tid * 16,  Al + 4096 + wid * 1024);
        gload16(Bsrc + tid * 16,         Bl + wid * 1024);
        gload16(Bsrc + 4096 + tid * 16,  Bl + 4096 + wid * 1024);
        gload16(Bsrc + 8192 + tid * 16,  Bl + 8192 + wid * 1024);
        gload16(Bsrc + 12288 + tid * 16, Bl + 12288 + wid * 1024);
    };

    stage(0, 0);
    __syncthreads();
    for (int s = 0; s < NSTEPS; ++s){
        if (s + 1 < NSTEPS) stage((s + 1) & 1, s + 1);
        const _Float16* Ab = (const _Float16*)(pool + (s & 1) * 8192);
        const _Float16* Bb = (const _Float16*)(pool + 16384 + (s & 1) * 16384);
        half8 a[4], b[8];
        #pragma unroll
        for (int mf = 0; mf < 4; ++mf)
            a[mf] = *(const half8*)(Ab + (wm * 64 + mf * 16 + lr) * 32 + lg * 8);
        #pragma unroll
        for (int nf = 0; nf < 8; ++nf)
            b[nf] = *(const half8*)(Bb + (wn * 128 + nf * 16 + lr) * 32 + lg * 8);
        #pragma unroll
        for (int mf = 0; mf < 4; ++mf)
            #pragma unroll
            for (int nf = 0; nf < 8; ++nf)
                acc[mf][nf] = __builtin_amdgcn_mfma_f32_16x16x32_f16(a[mf], b[nf], acc[mf][nf], 0, 0, 0);
        __syncthreads();
    }

    // ---- epilogue: scores -> sortable keys (8-bit col) -> per-row top2
    float csqv[8]; unsigned colb[8];
    #pragma unroll
    for (int nf = 0; nf < 8; ++nf){
        int col8 = wn * 128 + nf * 16 + lr;
        csqv[nf] = csq[nt * 256 + col8];
        colb[nf] = (unsigned)col8;
    }
    unsigned* mb = (unsigned*)pool;   // [2 wn][128 rows][2] = 2 KB (pool reused)
    #pragma unroll
    for (int mf = 0; mf < 4; ++mf){
        #pragma unroll
        for (int r = 0; r < 4; ++r){
            unsigned kk[8];
            #pragma unroll
            for (int nf = 0; nf < 8; ++nf){
                float sres = fmaf(-2.0f, acc[mf][nf][r], csqv[nf]);
                unsigned u = __float_as_uint(sres);
                unsigned msk = ((unsigned)((int)u >> 31)) | 0x80000000u;
                kk[nf] = ((u ^ msk) & 0xFFFFFF00u) | colb[nf];
            }
            unsigned lo01 = umin_(kk[0], kk[1]), hi01 = umax_(kk[0], kk[1]);
            unsigned lo23 = umin_(kk[2], kk[3]), hi23 = umax_(kk[2], kk[3]);
            unsigned lo45 = umin_(kk[4], kk[5]), hi45 = umax_(kk[4], kk[5]);
            unsigned lo67 = umin_(kk[6], kk[7]), hi67 = umax_(kk[6], kk[7]);
            unsigned a1 = umin_(lo01, lo23);
            unsigned a2 = umin_(umax_(lo01, lo23), umin_(hi01, hi23));
            unsigned b1 = umin_(lo45, lo67);
            unsigned b2 = umin_(umax_(lo45, lo67), umin_(hi45, hi67));
            unsigned m1 = umin_(a1, b1);
            unsigned m2 = umin_(umax_(a1, b1), umin_(a2, b2));
            #pragma unroll
            for (int dd = 1; dd <= 8; dd <<= 1){
                unsigned o1 = __shfl_xor(m1, dd, 64);
                unsigned o2 = __shfl_xor(m2, dd, 64);
                unsigned n1 = umin_(m1, o1);
                m2 = umin_(umax_(m1, o1), umin_(m2, o2));
                m1 = n1;
            }
            if (lr == 0){
                int row = wm * 64 + mf * 16 + lg * 4 + r;
                mb[(wn * 128 + row) * 2 + 0] = m1;
                mb[(wn * 128 + row) * 2 + 1] = m2;
            }
        }
    }
    __syncthreads();
    if (tid < 128){
        unsigned a1 = mb[tid * 2],        a2 = mb[tid * 2 + 1];
        unsigned b1 = mb[(128 + tid) * 2], b2 = mb[(128 + tid) * 2 + 1];
        unsigned g1 = umin_(a1, b1);
        unsigned g2 = umin_(umax_(a1, b1), umin_(a2, b2));
        int p = mt * 128 + tid;
        m1k[(size_t)nt * NPTS + p] = g1;
        m2k[(size_t)nt * NPTS + p] = g2;
    }
}

// ---- merge 4 tile-partials per point, flag near-ties
__global__ __launch_bounds__(256) void merge_kernel(
    const unsigned* __restrict__ m1k, const unsigned* __restrict__ m2k,
    int* __restrict__ nearest, int* __restrict__ flags, int* __restrict__ cnt)
{
    int pt = blockIdx.x * 256 + threadIdx.x;     // 32768
    unsigned g1 = 0xFFFFFFFFu, g2 = 0xFFFFFFFFu; int bt = 0;
    #pragma unroll
    for (int t = 0; t < 4; ++t){
        unsigned a = m1k[(size_t)t * NPTS + pt];
        unsigned b = m2k[(size_t)t * NPTS + pt];
        if (a < g1){ g2 = umin_(g1, b); g1 = a; bt = t; }
        else       { g2 = umin_(g2, a); }
    }
    nearest[pt] = bt * 256 + (int)(g1 & 0xFFu);
    if (unsortkey(g2) - unsortkey(g1) < MARGIN)
        flags[atomicAdd(cnt, 1)] = pt;
}

// ---- fp64 exact re-resolution for near-tie points: RPTS points per block,
// C read ONCE per RPTS points.
__global__ __launch_bounds__(256) void refine_kernel(
    const float* __restrict__ X, const float* __restrict__ C,
    const float* __restrict__ mean, const float* __restrict__ scale,
    const int* __restrict__ flags, const int* __restrict__ cnt,
    int* __restrict__ nearest)
{
    __shared__ double xs[RPTS][D];
    __shared__ double bm[256];
    __shared__ int    bk[256];

    const int nf = *cnt;
    for (int base = blockIdx.x * RPTS; base < nf; base += gridDim.x * RPTS){
        const int np = (nf - base < RPTS) ? (nf - base) : RPTS;
        __syncthreads();
        for (int idx = threadIdx.x; idx < np * D; idx += 256){
            int pp = idx >> 7, d = idx & 127;
            int p = flags[base + pp];
            xs[pp][d] = ((double)X[(size_t)p * D + d] - (double)mean[d]) / (double)scale[d];
        }
        __syncthreads();

        double best[RPTS]; int bestk[RPTS];
        #pragma unroll
        for (int pp = 0; pp < RPTS; ++pp){ best[pp] = 1.0e300; bestk[pp] = K_TOTAL; }

        for (int k = threadIdx.x; k < K_TOTAL; k += 256){
            const float* cp = C + (size_t)k * D;
            double s[RPTS] = {0.0, 0.0, 0.0, 0.0};
            for (int d = 0; d < D; d += 4){
                float4 cv = *(const float4*)(cp + d);
                double c0 = cv.x, c1 = cv.y, c2 = cv.z, c3 = cv.w;
                #pragma unroll
                for (int pp = 0; pp < RPTS; ++pp){
                    double d0 = xs[pp][d]     - c0;
                    double d1 = xs[pp][d + 1] - c1;
                    double d2 = xs[pp][d + 2] - c2;
                    double d3 = xs[pp][d + 3] - c3;
                    s[pp] += d0 * d0 + d1 * d1 + d2 * d2 + d3 * d3;
                }
            }
            #pragma unroll
            for (int pp = 0; pp < RPTS; ++pp)
                if (s[pp] < best[pp]){ best[pp] = s[pp]; bestk[pp] = k; }
        }

        for (int pp = 0; pp < np; ++pp){
            __syncthreads();
            bm[threadIdx.x] = best[pp]; bk[threadIdx.x] = bestk[pp];
            __syncthreads();
            for (int off = 128; off > 0; off >>= 1){
                if (threadIdx.x < off){
                    double ob = bm[threadIdx.x + off]; int ok = bk[threadIdx.x + off];
                    if (ob < bm[threadIdx.x] ||
                        (ob == bm[threadIdx.x] && ok < bk[threadIdx.x])){
                        bm[threadIdx.x] = ob; bk[threadIdx.x] = ok;
                    }
                }
                __syncthreads();
            }
            if (threadIdx.x == 0) nearest[flags[base + pp]] = bk[0];
        }
    }
}

// ---- full one-hot writeout: zeros + mask at nearest, coalesced float4 stores
__global__ __launch_bounds__(256) void writeout_kernel(
    const int* __restrict__ nearest, const float* __restrict__ mask,
    float4* __restrict__ out)
{
    const int r0 = blockIdx.x * 8;
    const int j = threadIdx.x;          // float4 index within the row (256 per row)
    const int base = j * 4;
    #pragma unroll
    for (int i = 0; i < 8; ++i) {
        const int row = r0 + i;
        const int nr = nearest[row];
        const float mv = mask[row];
        float4 v = {0.f, 0.f, 0.f, 0.f};
        const int off = nr - base;
        if (off >= 0 && off < 4) ((float*)&v)[off] = mv;
        out[(size_t)row * (K_TOTAL / 4) + j] = v;
    }
}

extern "C" void kernel_launch(void* const* d_in, const int* in_sizes, int n_in,
                              void* d_out, int out_size, void* d_ws, size_t ws_size,
                              hipStream_t stream) {
    const float* X     = (const float*)d_in[0];
    const float* mask  = (const float*)d_in[1];
    const float* C     = (const float*)d_in[2];
    const float* mean  = (const float*)d_in[3];
    const float* scale = (const float*)d_in[4];
    float* out = (float*)d_out;

    // scratch inside d_out (134 MB; we use < 20 MB, all overwritten at the end)
    char* sc = (char*)d_out;
    _Float16* Xh = (_Float16*)(sc);
    _Float16* Xl = (_Float16*)(sc + (8u << 20));
    _Float16* Ch = (_Float16*)(sc + (16u << 20));
    float*    csq = (float*)(sc + (16u << 20) + (512u << 10));
    unsigned* m1k = (unsigned*)(sc + (17u << 20));
    unsigned* m2k = (unsigned*)(sc + (18u << 20));
    int*      flags = (int*)(sc + (19u << 20));
    int*      cnt   = (int*)(sc + (19u << 20) + (128u << 10));
    int* nearest = (int*)d_ws;   // survives into the writeout

    split_kernel<<<532, 256, 0, stream>>>(X, mean, scale, C, Xh, Xl, Ch, csq, cnt);
    gemm_kernel<<<1024, 256, 0, stream>>>(sc, csq, m1k, m2k);
    merge_kernel<<<128, 256, 0, stream>>>(m1k, m2k, nearest, flags, cnt);
    refine_kernel<<<512, 256, 0, stream>>>(X, C, mean, scale, flags, cnt, nearest);
    writeout_kernel<<<NPTS / 8, 256, 0, stream>>>(nearest, mask, (float4*)out);
}

// Round 8
// 110.331 us; speedup vs baseline: 1.4694x; 1.0778x over previous
//
#include <hip/hip_runtime.h>

// ClusterPrior: B=8, N=4096, D=128, K=1024
// Round 8: single-term fp16 GEMM (K=128: dot ~= xh*ch). Dropped residual
// terms have score-difference RMS ~2.4e-2; MARGIN=0.1875 (~7.8 sigma, minus
// key-truncation slack 0.031 still >6 sigma). All near-ties re-resolved in
// exact fp64, so argmin stays exact.
// Scratch lives in d_out (fully overwritten by writeout). nearest[] in d_ws.

#define NPTS   32768
#define K_TOTAL 1024
#define D      128
#define MARGIN 0.1875f
#define NSTEPS 4
#define RPTS   4

typedef _Float16 half8 __attribute__((ext_vector_type(8)));
typedef float    f32x4 __attribute__((ext_vector_type(4)));

__device__ __forceinline__ unsigned umin_(unsigned a, unsigned b){ return a < b ? a : b; }
__device__ __forceinline__ unsigned umax_(unsigned a, unsigned b){ return a > b ? a : b; }

__device__ __forceinline__ float unsortkey(unsigned k){
    unsigned m = (k >> 31) ? 0x80000000u : 0xFFFFFFFFu;
    return __uint_as_float(k ^ m);
}

__device__ __forceinline__ void gload16(const void* g, void* l){
    __builtin_amdgcn_global_load_lds(
        (const __attribute__((address_space(1))) void*)g,
        (__attribute__((address_space(3))) void*)l, 16, 0, 0);
}

// ---- precompute (fused): blocks <512: standardize X -> fp16 [4][32768][32];
// blocks >=512: centroid fp16 [4][1024][32] + csq + zero cnt.
__global__ __launch_bounds__(256) void split_kernel(
    const float* __restrict__ X, const float* __restrict__ mean,
    const float* __restrict__ scale, const float* __restrict__ C,
    _Float16* __restrict__ Xh,
    _Float16* __restrict__ Ch, float* __restrict__ csq, int* __restrict__ cnt)
{
    if (blockIdx.x < 512){
        int gid = blockIdx.x * 256 + threadIdx.x;    // 131072
        int pt = gid >> 2;                           // point
        int c  = gid & 3;                            // k-chunk
        const float4* xs = (const float4*)(X + (size_t)pt * D + c * 32);
        const float4* mp = (const float4*)(mean + c * 32);
        const float4* sp = (const float4*)(scale + c * 32);
        half8 ho[4];
        #pragma unroll
        for (int j = 0; j < 8; ++j){
            float4 x = xs[j], m = mp[j], sv = sp[j];
            int v = j >> 1, e = (j & 1) * 4;
            ho[v][e]   = (_Float16)((x.x - m.x) / sv.x);
            ho[v][e+1] = (_Float16)((x.y - m.y) / sv.y);
            ho[v][e+2] = (_Float16)((x.z - m.z) / sv.z);
            ho[v][e+3] = (_Float16)((x.w - m.w) / sv.w);
        }
        half8* dh = (half8*)(Xh + ((size_t)c * NPTS + pt) * 32);
        #pragma unroll
        for (int v = 0; v < 4; ++v) dh[v] = ho[v];
    } else {
        int gid = (blockIdx.x - 512) * 256 + threadIdx.x;    // 5120
        if (gid == 0) *cnt = 0;
        if (gid < 4096){
            int k = gid >> 2;
            int c = gid & 3;
            const float4* xs = (const float4*)(C + (size_t)k * D + c * 32);
            half8 ho[4];
            #pragma unroll
            for (int j = 0; j < 8; ++j){
                float4 x = xs[j];
                int v = j >> 1, e = (j & 1) * 4;
                ho[v][e]   = (_Float16)x.x; ho[v][e+1] = (_Float16)x.y;
                ho[v][e+2] = (_Float16)x.z; ho[v][e+3] = (_Float16)x.w;
            }
            half8* dh = (half8*)(Ch + ((size_t)c * K_TOTAL + k) * 32);
            #pragma unroll
            for (int v = 0; v < 4; ++v) dh[v] = ho[v];
        } else if (gid < 5120){
            int k = gid - 4096;
            const float4* cp = (const float4*)(C + (size_t)k * D);
            float s = 0.f;
            #pragma unroll
            for (int j = 0; j < D / 4; ++j){
                float4 v = cp[j];
                s += v.x * v.x; s += v.y * v.y; s += v.z * v.z; s += v.w * v.w;
            }
            csq[k] = s;
        }
    }
}

// ---- fused GEMM (16x16x32 f16 MFMA) + per-tile argmin (min1/min2 keys)
// A = xh (K=128), B = ch. Block tile 128 pts x 256 cols; 4 waves (2M x 2N),
// wave tile 64x128 (acc 4x8 f32x4). grid 1024; XCD swizzle groups all 4
// nt-tiles of an mt-panel on one XCD.
__global__ __launch_bounds__(256, 2) void gemm_kernel(
    const char* __restrict__ scratch, const float* __restrict__ csq,
    unsigned* __restrict__ m1k, unsigned* __restrict__ m2k)
{
    __shared__ __align__(16) char pool[49152];   // A dbuf 2x8K @0, B dbuf 2x16K @16K
    const int tid = threadIdx.x;
    const int bid = blockIdx.x;
    // 8 XCDs round-robin: xcd r owns mt in [r*32,(r+1)*32); nt fastest inside.
    const int r_ = bid & 7, k2 = bid >> 3;          // k2 in [0,128)
    const int mt = r_ * 32 + (k2 >> 2), nt = k2 & 3;
    const int l = tid & 63, wid = tid >> 6;
    const int wm = wid >> 1, wn = wid & 1;
    const int lr = l & 15, lg = l >> 4;

    const char* Xh = scratch;
    const char* Ch = scratch + (16u << 20);

    f32x4 acc[4][8] = {};

    auto stage = [&](int buf, int s){
        const char* Asrc = Xh + ((size_t)s * NPTS   + (size_t)mt * 128) * 64;
        const char* Bsrc = Ch + ((size_t)s * K_TOTAL + (size_t)nt * 256) * 64;
        char* Al = pool + buf * 8192;
        char* Bl = pool + 16384 + buf * 16384;
        gload16(Asrc + tid * 16,         Al + wid * 1024);
        gload16(Asrc + 4096 + tid * 16,  Al + 4096 + wid * 1024);
        gload16(Bsrc + tid * 16,         Bl + wid * 1024);
        gload16(Bsrc + 4096 + tid * 16,  Bl + 4096 + wid * 1024);
        gload16(Bsrc + 8192 + tid * 16,  Bl + 8192 + wid * 1024);
        gload16(Bsrc + 12288 + tid * 16, Bl + 12288 + wid * 1024);
    };

    stage(0, 0);
    __syncthreads();
    for (int s = 0; s < NSTEPS; ++s){
        if (s + 1 < NSTEPS) stage((s + 1) & 1, s + 1);
        const _Float16* Ab = (const _Float16*)(pool + (s & 1) * 8192);
        const _Float16* Bb = (const _Float16*)(pool + 16384 + (s & 1) * 16384);
        half8 a[4], b[8];
        #pragma unroll
        for (int mf = 0; mf < 4; ++mf)
            a[mf] = *(const half8*)(Ab + (wm * 64 + mf * 16 + lr) * 32 + lg * 8);
        #pragma unroll
        for (int nf = 0; nf < 8; ++nf)
            b[nf] = *(const half8*)(Bb + (wn * 128 + nf * 16 + lr) * 32 + lg * 8);
        #pragma unroll
        for (int mf = 0; mf < 4; ++mf)
            #pragma unroll
            for (int nf = 0; nf < 8; ++nf)
                acc[mf][nf] = __builtin_amdgcn_mfma_f32_16x16x32_f16(a[mf], b[nf], acc[mf][nf], 0, 0, 0);
        __syncthreads();
    }

    // ---- epilogue: scores -> sortable keys (8-bit col) -> per-row top2
    float csqv[8]; unsigned colb[8];
    #pragma unroll
    for (int nf = 0; nf < 8; ++nf){
        int col8 = wn * 128 + nf * 16 + lr;
        csqv[nf] = csq[nt * 256 + col8];
        colb[nf] = (unsigned)col8;
    }
    unsigned* mb = (unsigned*)pool;   // [2 wn][128 rows][2] = 2 KB (pool reused)
    #pragma unroll
    for (int mf = 0; mf < 4; ++mf){
        #pragma unroll
        for (int r = 0; r < 4; ++r){
            unsigned kk[8];
            #pragma unroll
            for (int nf = 0; nf < 8; ++nf){
                float sres = fmaf(-2.0f, acc[mf][nf][r], csqv[nf]);
                unsigned u = __float_as_uint(sres);
                unsigned msk = ((unsigned)((int)u >> 31)) | 0x80000000u;
                kk[nf] = ((u ^ msk) & 0xFFFFFF00u) | colb[nf];
            }
            unsigned lo01 = umin_(kk[0], kk[1]), hi01 = umax_(kk[0], kk[1]);
            unsigned lo23 = umin_(kk[2], kk[3]), hi23 = umax_(kk[2], kk[3]);
            unsigned lo45 = umin_(kk[4], kk[5]), hi45 = umax_(kk[4], kk[5]);
            unsigned lo67 = umin_(kk[6], kk[7]), hi67 = umax_(kk[6], kk[7]);
            unsigned a1 = umin_(lo01, lo23);
            unsigned a2 = umin_(umax_(lo01, lo23), umin_(hi01, hi23));
            unsigned b1 = umin_(lo45, lo67);
            unsigned b2 = umin_(umax_(lo45, lo67), umin_(hi45, hi67));
            unsigned m1 = umin_(a1, b1);
            unsigned m2 = umin_(umax_(a1, b1), umin_(a2, b2));
            #pragma unroll
            for (int dd = 1; dd <= 8; dd <<= 1){
                unsigned o1 = __shfl_xor(m1, dd, 64);
                unsigned o2 = __shfl_xor(m2, dd, 64);
                unsigned n1 = umin_(m1, o1);
                m2 = umin_(umax_(m1, o1), umin_(m2, o2));
                m1 = n1;
            }
            if (lr == 0){
                int row = wm * 64 + mf * 16 + lg * 4 + r;
                mb[(wn * 128 + row) * 2 + 0] = m1;
                mb[(wn * 128 + row) * 2 + 1] = m2;
            }
        }
    }
    __syncthreads();
    if (tid < 128){
        unsigned a1 = mb[tid * 2],        a2 = mb[tid * 2 + 1];
        unsigned b1 = mb[(128 + tid) * 2], b2 = mb[(128 + tid) * 2 + 1];
        unsigned g1 = umin_(a1, b1);
        unsigned g2 = umin_(umax_(a1, b1), umin_(a2, b2));
        int p = mt * 128 + tid;
        m1k[(size_t)nt * NPTS + p] = g1;
        m2k[(size_t)nt * NPTS + p] = g2;
    }
}

// ---- merge 4 tile-partials per point, flag near-ties
__global__ __launch_bounds__(256) void merge_kernel(
    const unsigned* __restrict__ m1k, const unsigned* __restrict__ m2k,
    int* __restrict__ nearest, int* __restrict__ flags, int* __restrict__ cnt)
{
    int pt = blockIdx.x * 256 + threadIdx.x;     // 32768
    unsigned g1 = 0xFFFFFFFFu, g2 = 0xFFFFFFFFu; int bt = 0;
    #pragma unroll
    for (int t = 0; t < 4; ++t){
        unsigned a = m1k[(size_t)t * NPTS + pt];
        unsigned b = m2k[(size_t)t * NPTS + pt];
        if (a < g1){ g2 = umin_(g1, b); g1 = a; bt = t; }
        else       { g2 = umin_(g2, a); }
    }
    nearest[pt] = bt * 256 + (int)(g1 & 0xFFu);
    if (unsortkey(g2) - unsortkey(g1) < MARGIN)
        flags[atomicAdd(cnt, 1)] = pt;
}

// ---- fp64 exact re-resolution for near-tie points: RPTS points per block,
// C read ONCE per RPTS points.
__global__ __launch_bounds__(256) void refine_kernel(
    const float* __restrict__ X, const float* __restrict__ C,
    const float* __restrict__ mean, const float* __restrict__ scale,
    const int* __restrict__ flags, const int* __restrict__ cnt,
    int* __restrict__ nearest)
{
    __shared__ double xs[RPTS][D];
    __shared__ double bm[256];
    __shared__ int    bk[256];

    const int nf = *cnt;
    for (int base = blockIdx.x * RPTS; base < nf; base += gridDim.x * RPTS){
        const int np = (nf - base < RPTS) ? (nf - base) : RPTS;
        __syncthreads();
        for (int idx = threadIdx.x; idx < np * D; idx += 256){
            int pp = idx >> 7, d = idx & 127;
            int p = flags[base + pp];
            xs[pp][d] = ((double)X[(size_t)p * D + d] - (double)mean[d]) / (double)scale[d];
        }
        __syncthreads();

        double best[RPTS]; int bestk[RPTS];
        #pragma unroll
        for (int pp = 0; pp < RPTS; ++pp){ best[pp] = 1.0e300; bestk[pp] = K_TOTAL; }

        for (int k = threadIdx.x; k < K_TOTAL; k += 256){
            const float* cp = C + (size_t)k * D;
            double s[RPTS] = {0.0, 0.0, 0.0, 0.0};
            for (int d = 0; d < D; d += 4){
                float4 cv = *(const float4*)(cp + d);
                double c0 = cv.x, c1 = cv.y, c2 = cv.z, c3 = cv.w;
                #pragma unroll
                for (int pp = 0; pp < RPTS; ++pp){
                    double d0 = xs[pp][d]     - c0;
                    double d1 = xs[pp][d + 1] - c1;
                    double d2 = xs[pp][d + 2] - c2;
                    double d3 = xs[pp][d + 3] - c3;
                    s[pp] += d0 * d0 + d1 * d1 + d2 * d2 + d3 * d3;
                }
            }
            #pragma unroll
            for (int pp = 0; pp < RPTS; ++pp)
                if (s[pp] < best[pp]){ best[pp] = s[pp]; bestk[pp] = k; }
        }

        for (int pp = 0; pp < np; ++pp){
            __syncthreads();
            bm[threadIdx.x] = best[pp]; bk[threadIdx.x] = bestk[pp];
            __syncthreads();
            for (int off = 128; off > 0; off >>= 1){
                if (threadIdx.x < off){
                    double ob = bm[threadIdx.x + off]; int ok = bk[threadIdx.x + off];
                    if (ob < bm[threadIdx.x] ||
                        (ob == bm[threadIdx.x] && ok < bk[threadIdx.x])){
                        bm[threadIdx.x] = ob; bk[threadIdx.x] = ok;
                    }
                }
                __syncthreads();
            }
            if (threadIdx.x == 0) nearest[flags[base + pp]] = bk[0];
        }
    }
}

// ---- full one-hot writeout: zeros + mask at nearest, coalesced float4 stores
__global__ __launch_bounds__(256) void writeout_kernel(
    const int* __restrict__ nearest, const float* __restrict__ mask,
    float4* __restrict__ out)
{
    const int r0 = blockIdx.x * 8;
    const int j = threadIdx.x;          // float4 index within the row (256 per row)
    const int base = j * 4;
    #pragma unroll
    for (int i = 0; i < 8; ++i) {
        const int row = r0 + i;
        const int nr = nearest[row];
        const float mv = mask[row];
        float4 v = {0.f, 0.f, 0.f, 0.f};
        const int off = nr - base;
        if (off >= 0 && off < 4) ((float*)&v)[off] = mv;
        out[(size_t)row * (K_TOTAL / 4) + j] = v;
    }
}

extern "C" void kernel_launch(void* const* d_in, const int* in_sizes, int n_in,
                              void* d_out, int out_size, void* d_ws, size_t ws_size,
                              hipStream_t stream) {
    const float* X     = (const float*)d_in[0];
    const float* mask  = (const float*)d_in[1];
    const float* C     = (const float*)d_in[2];
    const float* mean  = (const float*)d_in[3];
    const float* scale = (const float*)d_in[4];
    float* out = (float*)d_out;

    // scratch inside d_out (134 MB; we use < 20 MB, all overwritten at the end)
    char* sc = (char*)d_out;
    _Float16* Xh = (_Float16*)(sc);
    _Float16* Ch = (_Float16*)(sc + (16u << 20));
    float*    csq = (float*)(sc + (16u << 20) + (512u << 10));
    unsigned* m1k = (unsigned*)(sc + (17u << 20));
    unsigned* m2k = (unsigned*)(sc + (18u << 20));
    int*      flags = (int*)(sc + (19u << 20));
    int*      cnt   = (int*)(sc + (19u << 20) + (128u << 10));
    int* nearest = (int*)d_ws;   // survives into the writeout

    split_kernel<<<532, 256, 0, stream>>>(X, mean, scale, C, Xh, Ch, csq, cnt);
    gemm_kernel<<<1024, 256, 0, stream>>>(sc, csq, m1k, m2k);
    merge_kernel<<<128, 256, 0, stream>>>(m1k, m2k, nearest, flags, cnt);
    refine_kernel<<<512, 256, 0, stream>>>(X, C, mean, scale, flags, cnt, nearest);
    writeout_kernel<<<NPTS / 8, 256, 0, stream>>>(nearest, mask, (float4*)out);
}